// Round 10
// baseline (29.251 us; speedup 1.0000x reference)
//
#include <hip/hip_runtime.h>

#define BSZ  64
#define NF   4
#define NCLS 4
#define PLO  256
#define PHI  16384
#define KN   9
#define W27  27
#define CPX  64               // pixels per block == wave size
#define XSL  80               // NF * 2 cell-rows * 10 cell-cols

__global__ __launch_bounds__(64, 1) void rect_up_kernel(
    const float* __restrict__ x,         // (B, NF*PLO)
    const float* __restrict__ orog,      // (B, PHI, 2)
    const float* __restrict__ wmap,      // (NCLS, NF, PHI, KN, 3)
    const float* __restrict__ bias_low,  // (NCLS, NF, PLO)
    const float* __restrict__ bias_high, // (NCLS, NF, PHI)
    const float* __restrict__ bias_orog, // (NCLS, 2, PHI)
    const int*   __restrict__ cls_ids,   // (B,)
    const int*   __restrict__ nb,        // (PHI, KN)
    float* __restrict__ out)             // (B, NF, PHI)
{
    // single-wave block: all LDS traffic is wave-ordered -> zero barriers
    __shared__ float wst[NF * CPX * W27];    // 27648 B (prologue staging)
    __shared__ float xsb[2][XSL];            // 640 B (x slice, dbuf)

    const int bid   = blockIdx.x;
    const int cls   = bid & 3;
    const int chunk = bid >> 2;              // 0..255
    const int lane  = threadIdx.x;           // 0..63
    const int p     = chunk * CPX + lane;
    const int pi    = chunk >> 1;            // pixel row (uniform)
    const int j0    = (chunk & 1) * 64;      // first column
    const int pj    = j0 + lane;

    // ---- (1) issue weight global->LDS staging FIRST --------------------
    #pragma unroll
    for (int f = 0; f < NF; ++f) {
        const float4* s4 = reinterpret_cast<const float4*>(
            wmap + ((size_t)(cls * NF + f) * PHI + chunk * CPX) * W27);
        float4* d4 = reinterpret_cast<float4*>(wst + f * (CPX * W27));
        #pragma unroll
        for (int i = 0; i < 7; ++i) {
            const int idx = lane + i * 64;   // 432 float4 per feature
            if (idx < (CPX * W27) / 4) d4[idx] = s4[idx];
        }
    }

    // ---- class membership (wave width == BSZ == 64) --------------------
    const unsigned long long cmask = __ballot(cls_ids[lane] == cls);
    if (cmask == 0ULL) return;

    // ---- batch-invariant geometry --------------------------------------
    const int CR0 = (pi - 2 < 0 ? 0 : pi - 2) >> 3;
    const int CR1 = (pi + 2 > 127 ? 127 : pi + 2) >> 3;
    const int XC0 = (j0 - 2 < 0 ? 0 : j0 - 2) >> 3;
    const int ccl0 = ((pj - 2 < 0 ? 0 : pj - 2) >> 3) - XC0;   // 0..8

    int nbOff[KN], sel[KN];
    #pragma unroll
    for (int k = 0; k < KN; ++k) {
        const int n = nb[p * KN + k];
        nbOff[k] = n * 8;                    // byte offset in a batch's orog
        const int rr = (((n >> 7) >> 3) != CR0) ? 1 : 0;
        const int cc = (((n & 127) >> 3) != (XC0 + ccl0)) ? 1 : 0;
        sel[k] = rr * 2 + cc;
    }

    // ---- batch scan ----------------------------------------------------
    unsigned long long m = cmask;
    int b = __ffsll(m) - 1;  m &= m - 1;

    // ---- first batch's orog loads (fly under weight stream) ------------
    float o0[KN], o1[KN];
    {
        const char* ob = (const char*)orog + (size_t)b * (PHI * 8);
        #pragma unroll
        for (int k = 0; k < KN; ++k) {
            const float2 v = *reinterpret_cast<const float2*>(ob + nbOff[k]);
            o0[k] = v.x; o1[k] = v.y;
        }
    }

    // ---- xs stager roles: slots lane and 64+lane (lane<16) -------------
    int xIdx0, xIdx1 = 0; float xbl0, xbl1 = 0.f;
    {
        const int s = lane, ff = s / 20, q = s % 20, rr = q / 10, c2 = q % 10;
        const int crow = rr ? CR1 : CR0;
        int col = XC0 + c2; col = col > 15 ? 15 : col;
        xIdx0 = ff * PLO + crow * 16 + col;
        xbl0  = bias_low[cls * (NF * PLO) + xIdx0];
    }
    if (lane < XSL - 64) {
        const int s = 64 + lane, ff = s / 20, q = s % 20, rr = q / 10, c2 = q % 10;
        const int crow = rr ? CR1 : CR0;
        int col = XC0 + c2; col = col > 15 ? 15 : col;
        xIdx1 = ff * PLO + crow * 16 + col;
        xbl1  = bias_low[cls * (NF * PLO) + xIdx1];
    }
    float xv0 = x[b * (NF * PLO) + xIdx0];
    float xv1 = (lane < XSL - 64) ? x[b * (NF * PLO) + xIdx1] : 0.f;

    // ---- bias_orog gathers (batch-invariant) ---------------------------
    float yob0[KN], yob1[KN];
    #pragma unroll
    for (int k = 0; k < KN; ++k) {
        const int n = nbOff[k] >> 3;
        yob0[k] = bias_orog[(cls * 2 + 0) * PHI + n];
        yob1[k] = bias_orog[(cls * 2 + 1) * PHI + n];
    }

    // ---- unpack weights (wave-ordered LDS RAW) + fold biases -----------
    float w1[NF][KN], w2[NF][KN], wcy[NF][4], accInit[NF];
    #pragma unroll
    for (int f = 0; f < NF; ++f) {
        #pragma unroll
        for (int j = 0; j < 4; ++j) wcy[f][j] = 0.f;
        #pragma unroll
        for (int k = 0; k < KN; ++k) {
            const float w0 = wst[f * (CPX * W27) + lane * W27 + 3 * k];
            w1[f][k] = wst[f * (CPX * W27) + lane * W27 + 3 * k + 1];
            w2[f][k] = wst[f * (CPX * W27) + lane * W27 + 3 * k + 2];
            #pragma unroll
            for (int j = 0; j < 4; ++j)
                wcy[f][j] += (sel[k] == j) ? w0 : 0.f;   // static idx only
        }
        float a = bias_high[(cls * NF + f) * PHI + p];
        #pragma unroll
        for (int k = 0; k < KN; ++k)
            a -= yob0[k] * w1[f][k] + yob1[k] * w2[f][k];
        accInit[f] = a;
    }

    // ---- stage first xs (pre-biased) ------------------------------------
    xsb[0][lane] = xv0 - xbl0;
    if (lane < XSL - 64) xsb[0][64 + lane] = xv1 - xbl1;

    // ---- batch loop: barrier-free, next batch prefetched ----------------
    int cur = 0;
    while (true) {
        const int bn = m ? (__ffsll(m) - 1) : -1;  if (m) m &= m - 1;

        float n0[KN], n1[KN], nx0 = 0.f, nx1 = 0.f;
        if (bn >= 0) {                       // issue next batch's loads
            const char* ob = (const char*)orog + (size_t)bn * (PHI * 8);
            #pragma unroll
            for (int k = 0; k < KN; ++k) {
                const float2 v = *reinterpret_cast<const float2*>(ob + nbOff[k]);
                n0[k] = v.x; n1[k] = v.y;
            }
            nx0 = x[bn * (NF * PLO) + xIdx0];
            if (lane < XSL - 64) nx1 = x[bn * (NF * PLO) + xIdx1];
        }

        // compute current batch (all 4 features from registers + tiny LDS)
        const float* xs = xsb[cur];
        #pragma unroll
        for (int f = 0; f < NF; ++f) {
            const int base0 = f * 20 + ccl0;         // pair reads: ds_read2
            float acc = accInit[f]
                + xs[base0]      * wcy[f][0]
                + xs[base0 + 1]  * wcy[f][1]         // wcy[1]==0 if same cell
                + xs[base0 + 10] * wcy[f][2]
                + xs[base0 + 11] * wcy[f][3];
            #pragma unroll
            for (int k = 0; k < KN; ++k)
                acc += o0[k] * w1[f][k] + o1[k] * w2[f][k];
            out[((size_t)b * NF + f) * PHI + p] = acc;
        }

        if (bn < 0) break;

        // write next xs into the other buffer (wave-ordered, no barrier)
        xsb[cur ^ 1][lane] = nx0 - xbl0;
        if (lane < XSL - 64) xsb[cur ^ 1][64 + lane] = nx1 - xbl1;
        #pragma unroll
        for (int k = 0; k < KN; ++k) { o0[k] = n0[k]; o1[k] = n1[k]; }
        b = bn; cur ^= 1;
    }
}

extern "C" void kernel_launch(void* const* d_in, const int* in_sizes, int n_in,
                              void* d_out, int out_size, void* d_ws, size_t ws_size,
                              hipStream_t stream) {
    const float* x         = (const float*)d_in[0];
    const float* orog      = (const float*)d_in[1];
    const float* wmap      = (const float*)d_in[2];
    const float* bias_low  = (const float*)d_in[3];
    const float* bias_high = (const float*)d_in[4];
    const float* bias_orog = (const float*)d_in[5];
    const int*   cls_ids   = (const int*)d_in[6];
    const int*   nb        = (const int*)d_in[7];
    float* out = (float*)d_out;

    // grid: NCLS x 256 chunks = 1024 single-wave blocks (4/CU);
    // each thread owns one pixel for all 4 features.
    dim3 grid(NCLS * (PHI / CPX));
    dim3 block(64);
    rect_up_kernel<<<grid, block, 0, stream>>>(
        x, orog, wmap, bias_low, bias_high, bias_orog, cls_ids, nb, out);
}